// Round 1
// baseline (1630.829 us; speedup 1.0000x reference)
//
#include <hip/hip_runtime.h>
#include <math.h>

// ---------------- CSR build ----------------

__global__ __launch_bounds__(256)
void hist_kernel(const int* __restrict__ dst, int* __restrict__ cnt, int E) {
    int e = blockIdx.x * 256 + threadIdx.x;
    if (e < E) atomicAdd(&cnt[dst[e]], 1);
}

__global__ __launch_bounds__(1024)
void scan_kernel(const int* __restrict__ cnt, int* __restrict__ off, int n) {
    __shared__ int lds[1024];
    int t = threadIdx.x;
    int chunk = (n + 1023) >> 10;
    int begin = t * chunk;
    int end = min(begin + chunk, n);
    if (end < begin) end = begin;
    int s = 0;
    for (int i = begin; i < end; ++i) s += cnt[i];
    lds[t] = s;
    __syncthreads();
    for (int d = 1; d < 1024; d <<= 1) {
        int v = (t >= d) ? lds[t - d] : 0;
        __syncthreads();
        lds[t] += v;
        __syncthreads();
    }
    int pre = (t == 0) ? 0 : lds[t - 1];
    for (int i = begin; i < end; ++i) { off[i] = pre; pre += cnt[i]; }
    if (t == 1023) off[n] = pre;   // total = E
}

__global__ __launch_bounds__(256)
void scatter_kernel(const int* __restrict__ src, const int* __restrict__ dst,
                    int* __restrict__ cur, const int* __restrict__ off,
                    int* __restrict__ csr, int E) {
    int e = blockIdx.x * 256 + threadIdx.x;
    if (e < E) {
        int d = dst[e];
        int pos = off[d] + atomicAdd(&cur[d], 1);
        csr[pos] = src[e];
    }
}

// ---------------- per-dst online-softmax aggregation ----------------
// aggr[d][c] = sum_j exp(v_j - max) * v_j / sum_j exp(v_j - max),  v_j = x[csr[j]][c]
// One block (256 threads = 256 channels) per destination node.

__global__ __launch_bounds__(256)
void sage_aggr_kernel(const float* __restrict__ x, const int* __restrict__ csr,
                      const int* __restrict__ off, float* __restrict__ aggr) {
    int d = blockIdx.x;
    int c = threadIdx.x;
    int s0 = off[d], s1 = off[d + 1];
    float m = -INFINITY, sumE = 0.f, sumEM = 0.f;
    for (int j = s0; j < s1; ++j) {
        int s = csr[j];
        float v = x[(size_t)s * 256 + c];
        float nm = fmaxf(m, v);
        float r = __expf(m - nm);   // 0 on first iter (m=-inf), else <=1
        float p = __expf(v - nm);
        sumE  = sumE  * r + p;
        sumEM = sumEM * r + p * v;
        m = nm;
    }
    aggr[(size_t)d * 256 + c] = (s1 > s0) ? (sumEM / sumE) : 0.f;
}

// ---------------- fused GEMM: C = act(A@W [+ A2@W2] + bias) ----------------
// A:[M,K1], W:[K1,N], A2:[M,K2], W2:[K2,N], row-major. N % 64 == 0, K % 16 == 0.

__global__ __launch_bounds__(256)
void gemm_kernel(const float* __restrict__ A, const float* __restrict__ W,
                 const float* __restrict__ A2, const float* __restrict__ W2,
                 const float* __restrict__ bias, float* __restrict__ C,
                 int M, int N, int K1, int K2, int act) {
    __shared__ __align__(16) float As[16][64];
    __shared__ __align__(16) float Bs[16][64];
    int bm = blockIdx.y * 64;
    int bn = blockIdx.x * 64;
    int tid = threadIdx.x;
    int tx = tid & 15, ty = tid >> 4;
    float acc[4][4] = {};
    int Kt = K1 + K2;
    for (int k0 = 0; k0 < Kt; k0 += 16) {
        const float* Ap; const float* Wp; int kk, Ks;
        if (k0 < K1) { Ap = A;  Wp = W;  kk = k0;      Ks = K1; }
        else         { Ap = A2; Wp = W2; kk = k0 - K1; Ks = K2; }
        // A tile: 64 rows x 16 cols, one float4 per thread
        {
            int row = tid >> 2, c4 = (tid & 3) * 4;
            int grow = bm + row;
            float4 v = make_float4(0.f, 0.f, 0.f, 0.f);
            if (grow < M) v = *(const float4*)(Ap + (size_t)grow * Ks + kk + c4);
            As[c4 + 0][row] = v.x; As[c4 + 1][row] = v.y;
            As[c4 + 2][row] = v.z; As[c4 + 3][row] = v.w;
        }
        // W tile: 16 rows x 64 cols, one float4 per thread
        {
            int wr = tid >> 4, wc = (tid & 15) * 4;
            *(float4*)(&Bs[wr][wc]) = *(const float4*)(Wp + (size_t)(kk + wr) * N + bn + wc);
        }
        __syncthreads();
        #pragma unroll
        for (int k = 0; k < 16; ++k) {
            float4 a = *(const float4*)(&As[k][ty * 4]);
            float4 b = *(const float4*)(&Bs[k][tx * 4]);
            float av[4] = {a.x, a.y, a.z, a.w};
            float bv[4] = {b.x, b.y, b.z, b.w};
            #pragma unroll
            for (int i = 0; i < 4; ++i)
                #pragma unroll
                for (int j = 0; j < 4; ++j)
                    acc[i][j] += av[i] * bv[j];
        }
        __syncthreads();
    }
    #pragma unroll
    for (int i = 0; i < 4; ++i) {
        int row = bm + ty * 4 + i;
        if (row >= M) continue;
        #pragma unroll
        for (int j = 0; j < 4; ++j) {
            int col = bn + tx * 4 + j;
            float v = acc[i][j] + bias[col];
            if (act == 1) v = fmaxf(v, 0.f);
            else if (act == 2) v = tanhf(v);
            C[(size_t)row * N + col] = v;
        }
    }
}

// ---------------- launch ----------------

extern "C" void kernel_launch(void* const* d_in, const int* in_sizes, int n_in,
                              void* d_out, int out_size, void* d_ws, size_t ws_size,
                              hipStream_t stream) {
    const float* feat = (const float*)d_in[0];
    const int*   einfo = (const int*)d_in[1];
    const float* W1 = (const float*)d_in[2];  const float* b1 = (const float*)d_in[3];
    const float* W2 = (const float*)d_in[4];  const float* b2 = (const float*)d_in[5];
    const float* W3 = (const float*)d_in[6];  const float* b3 = (const float*)d_in[7];
    const float* Wl1 = (const float*)d_in[8]; const float* bl1 = (const float*)d_in[9];
    const float* Wr1 = (const float*)d_in[10];
    const float* WlH = (const float*)d_in[11]; const float* blH = (const float*)d_in[12];
    const float* WrH = (const float*)d_in[13];
    const float* Wl2 = (const float*)d_in[14]; const float* bl2 = (const float*)d_in[15];
    const float* Wr2 = (const float*)d_in[16];
    const float* Wp1 = (const float*)d_in[17]; const float* bp1 = (const float*)d_in[18];
    const float* Wp2 = (const float*)d_in[19]; const float* bp2 = (const float*)d_in[20];
    const float* Wp3 = (const float*)d_in[21]; const float* bp3 = (const float*)d_in[22];

    const int IN_DIM = 512, HID = 256, OUT = 128;
    const int N = in_sizes[0] / IN_DIM;   // 50000
    const int E = in_sizes[1] / 2;        // 400000
    const int* src = einfo;
    const int* dst = einfo + E;

    float* bufA = (float*)d_ws;
    float* bufB = bufA + (size_t)N * HID;
    float* bufC = bufB + (size_t)N * HID;
    int* ioff = (int*)(bufC + (size_t)N * HID);
    int* icnt = ioff + (N + 1);
    int* icur = icnt + N;
    int* csr  = icur + N;

    // CSR (by dst) build — recomputed every call (no cross-call state)
    hipMemsetAsync(icnt, 0, (size_t)N * sizeof(int), stream);
    hipMemsetAsync(icur, 0, (size_t)N * sizeof(int), stream);
    hist_kernel<<<(E + 255) / 256, 256, 0, stream>>>(dst, icnt, E);
    scan_kernel<<<1, 1024, 0, stream>>>(icnt, ioff, N);
    scatter_kernel<<<(E + 255) / 256, 256, 0, stream>>>(src, dst, icur, ioff, csr, E);

    auto gemm = [&](const float* A, const float* Wm, const float* A2, const float* W2m,
                    const float* bias, float* C, int M, int Nc, int K1, int K2, int act) {
        dim3 g(Nc / 64, (M + 63) / 64);
        gemm_kernel<<<g, 256, 0, stream>>>(A, Wm, A2, W2m, bias, C, M, Nc, K1, K2, act);
    };

    // MLP stem
    gemm(feat, W1, nullptr, nullptr, b1, bufA, N, HID, IN_DIM, 0, 1);
    gemm(bufA, W2, nullptr, nullptr, b2, bufB, N, HID, HID, 0, 1);
    gemm(bufB, W3, nullptr, nullptr, b3, bufA, N, HID, HID, 0, 1);

    // SAGE layer 1: x = bufA
    sage_aggr_kernel<<<N, 256, 0, stream>>>(bufA, csr, ioff, bufC);
    gemm(bufC, Wl1, bufA, Wr1, bl1, bufB, N, HID, HID, HID, 1);

    // SAGE layer 2: x = bufB
    sage_aggr_kernel<<<N, 256, 0, stream>>>(bufB, csr, ioff, bufC);
    gemm(bufC, WlH, bufB, WrH, blH, bufA, N, HID, HID, HID, 1);

    // SAGE layer 3: x = bufA
    sage_aggr_kernel<<<N, 256, 0, stream>>>(bufA, csr, ioff, bufC);
    gemm(bufC, Wl2, bufA, Wr2, bl2, bufB, N, HID, HID, HID, 1);

    // MLP head
    gemm(bufB, Wp1, nullptr, nullptr, bp1, bufA, N, HID, HID, 0, 1);
    gemm(bufA, Wp2, nullptr, nullptr, bp2, bufB, N, HID, HID, 0, 1);
    gemm(bufB, Wp3, nullptr, nullptr, bp3, (float*)d_out, N, OUT, HID, 0, 2);
}

// Round 2
// 899.160 us; speedup vs baseline: 1.8137x; 1.8137x over previous
//
#include <hip/hip_runtime.h>
#include <hip/hip_bf16.h>
#include <math.h>

typedef short s8v __attribute__((ext_vector_type(8)));
typedef float f32x4 __attribute__((ext_vector_type(4)));

__device__ __forceinline__ ushort f2bf(float f) {
    __hip_bfloat16 h = __float2bfloat16(f);
    return *reinterpret_cast<ushort*>(&h);
}
__device__ __forceinline__ float bf2f(ushort u) {
    return __uint_as_float(((unsigned)u) << 16);
}

// ---------------- CSR build ----------------

__global__ __launch_bounds__(256)
void hist_kernel(const int* __restrict__ dst, int* __restrict__ cnt, int E) {
    int e = blockIdx.x * 256 + threadIdx.x;
    if (e < E) atomicAdd(&cnt[dst[e]], 1);
}

__global__ __launch_bounds__(1024)
void scan_kernel(const int* __restrict__ cnt, int* __restrict__ off, int n) {
    __shared__ int lds[1024];
    int t = threadIdx.x;
    int chunk = (n + 1023) >> 10;
    int begin = t * chunk;
    int end = min(begin + chunk, n);
    if (end < begin) end = begin;
    int s = 0;
    for (int i = begin; i < end; ++i) s += cnt[i];
    lds[t] = s;
    __syncthreads();
    for (int d = 1; d < 1024; d <<= 1) {
        int v = (t >= d) ? lds[t - d] : 0;
        __syncthreads();
        lds[t] += v;
        __syncthreads();
    }
    int pre = (t == 0) ? 0 : lds[t - 1];
    for (int i = begin; i < end; ++i) { off[i] = pre; pre += cnt[i]; }
    if (t == 1023) off[n] = pre;
}

__global__ __launch_bounds__(256)
void scatter_kernel(const int* __restrict__ src, const int* __restrict__ dst,
                    int* __restrict__ cur, const int* __restrict__ off,
                    int* __restrict__ csr, int E) {
    int e = blockIdx.x * 256 + threadIdx.x;
    if (e < E) {
        int d = dst[e];
        int pos = off[d] + atomicAdd(&cur[d], 1);
        csr[pos] = src[e];
    }
}

// ---------------- weight prep: transpose + hi/lo bf16 split ----------------

struct PrepArgs {
    const float* W[12];
    ushort* H[12];
    ushort* L[12];
    int end[12];     // exclusive prefix sums of element counts
    int Kv[12];
    int nshift[12];  // log2(N)
};

__global__ __launch_bounds__(256)
void prep_weights(PrepArgs a, int total) {
    int id = blockIdx.x * 256 + threadIdx.x;
    if (id >= total) return;
    int s = 0;
    #pragma unroll
    for (int i = 0; i < 12; ++i) if (id >= a.end[i]) s = i + 1;
    int base = (s == 0) ? 0 : a.end[s - 1];
    int e = id - base;
    int K = a.Kv[s];
    int Nmask = (1 << a.nshift[s]) - 1;
    int n = e & Nmask;
    int k = e >> a.nshift[s];
    float w = a.W[s][(size_t)k * (Nmask + 1) + n];
    ushort hi = f2bf(w);
    ushort lo = f2bf(w - bf2f(hi));
    a.H[s][(size_t)n * K + k] = hi;
    a.L[s][(size_t)n * K + k] = lo;
}

// ---------------- per-dst online-softmax aggregation (float4) ----------------

__global__ __launch_bounds__(256)
void sage_aggr4(const float* __restrict__ x, const int* __restrict__ csr,
                const int* __restrict__ off, float* __restrict__ aggr, int nN) {
    int node = blockIdx.x * 4 + (threadIdx.x >> 6);
    if (node >= nN) return;
    int c4 = (threadIdx.x & 63) * 4;
    int s0 = off[node], s1 = off[node + 1];
    float m0 = -INFINITY, m1 = -INFINITY, m2 = -INFINITY, m3 = -INFINITY;
    float se0 = 0, se1 = 0, se2 = 0, se3 = 0;
    float sm0 = 0, sm1 = 0, sm2 = 0, sm3 = 0;
    for (int j = s0; j < s1; ++j) {
        int s = csr[j];
        float4 v = *(const float4*)(x + (size_t)s * 256 + c4);
        { float nm = fmaxf(m0, v.x); float r = __expf(m0 - nm); float p = __expf(v.x - nm);
          se0 = se0 * r + p; sm0 = sm0 * r + p * v.x; m0 = nm; }
        { float nm = fmaxf(m1, v.y); float r = __expf(m1 - nm); float p = __expf(v.y - nm);
          se1 = se1 * r + p; sm1 = sm1 * r + p * v.y; m1 = nm; }
        { float nm = fmaxf(m2, v.z); float r = __expf(m2 - nm); float p = __expf(v.z - nm);
          se2 = se2 * r + p; sm2 = sm2 * r + p * v.z; m2 = nm; }
        { float nm = fmaxf(m3, v.w); float r = __expf(m3 - nm); float p = __expf(v.w - nm);
          se3 = se3 * r + p; sm3 = sm3 * r + p * v.w; m3 = nm; }
    }
    float4 o;
    o.x = (s1 > s0) ? sm0 / se0 : 0.f;
    o.y = (s1 > s0) ? sm1 / se1 : 0.f;
    o.z = (s1 > s0) ? sm2 / se2 : 0.f;
    o.w = (s1 > s0) ? sm3 / se3 : 0.f;
    *(float4*)(aggr + (size_t)node * 256 + c4) = o;
}

// ---------------- split-bf16 MFMA GEMM ----------------
// C = act( [A1|A2] @ [W1;W2] + bias ), A fp32 row-major, W pre-transposed+split
// ([N][K] bf16 hi/lo). Tile 128x128, BK=32, 4 waves (each 64x64 = 4x4 frags).
// 3-term split product: Ah*Bh + Ah*Bl + Al*Bh, fp32 accumulate.

__global__ __launch_bounds__(256)
void gemm_split_kernel(const float* __restrict__ A1, int K1,
                       const float* __restrict__ A2, int K2,
                       const ushort* __restrict__ W1H, const ushort* __restrict__ W1L,
                       const ushort* __restrict__ W2H, const ushort* __restrict__ W2L,
                       const float* __restrict__ bias, float* __restrict__ Cout,
                       int M, int N, int act) {
    __shared__ __align__(16) ushort AsH[4][128][8];
    __shared__ __align__(16) ushort AsL[4][128][8];
    __shared__ __align__(16) ushort BsH[4][128][8];
    __shared__ __align__(16) ushort BsL[4][128][8];

    const int tid = threadIdx.x;
    const int lane = tid & 63;
    const int wid = tid >> 6;
    const int wm = wid >> 1, wn = wid & 1;
    const int li = lane & 15, kg = lane >> 4;
    const int bm = blockIdx.y * 128;
    const int bn = blockIdx.x * 128;

    f32x4 acc[4][4] = {};

    const int Kt = K1 + K2;
    const int sm = tid >> 1;        // staging row (A) / col (B) 0..127
    const int kh = (tid & 1) * 16;  // k offset within BK=32
    const int kga = kh >> 3;        // first k-group (0 or 2)

    for (int k0 = 0; k0 < Kt; k0 += 32) {
        const float* Ap; const ushort *WH, *WL; int Ks, kk;
        if (k0 < K1) { Ap = A1; WH = W1H; WL = W1L; Ks = K1; kk = k0; }
        else         { Ap = A2; WH = W2H; WL = W2L; Ks = K2; kk = k0 - K1; }

        // stage A: 16 fp32 per thread -> hi/lo bf16
        {
            int gm = bm + sm;
            float4 f0 = {}, f1 = {}, f2 = {}, f3 = {};
            if (gm < M) {
                const float* p = Ap + (size_t)gm * Ks + kk + kh;
                f0 = *(const float4*)(p);
                f1 = *(const float4*)(p + 4);
                f2 = *(const float4*)(p + 8);
                f3 = *(const float4*)(p + 12);
            }
            float v[16] = {f0.x, f0.y, f0.z, f0.w, f1.x, f1.y, f1.z, f1.w,
                           f2.x, f2.y, f2.z, f2.w, f3.x, f3.y, f3.z, f3.w};
            s8v h0, h1, l0, l1;
            #pragma unroll
            for (int e = 0; e < 8; ++e) {
                ushort h = f2bf(v[e]);
                h0[e] = (short)h;
                l0[e] = (short)f2bf(v[e] - bf2f(h));
            }
            #pragma unroll
            for (int e = 0; e < 8; ++e) {
                ushort h = f2bf(v[8 + e]);
                h1[e] = (short)h;
                l1[e] = (short)f2bf(v[8 + e] - bf2f(h));
            }
            *(s8v*)&AsH[kga][sm][0]     = h0;
            *(s8v*)&AsH[kga + 1][sm][0] = h1;
            *(s8v*)&AsL[kga][sm][0]     = l0;
            *(s8v*)&AsL[kga + 1][sm][0] = l1;
        }
        // stage B: copy pre-split weights
        {
            const ushort* pH = WH + (size_t)(bn + sm) * Ks + kk + kh;
            const ushort* pL = WL + (size_t)(bn + sm) * Ks + kk + kh;
            *(s8v*)&BsH[kga][sm][0]     = *(const s8v*)(pH);
            *(s8v*)&BsH[kga + 1][sm][0] = *(const s8v*)(pH + 8);
            *(s8v*)&BsL[kga][sm][0]     = *(const s8v*)(pL);
            *(s8v*)&BsL[kga + 1][sm][0] = *(const s8v*)(pL + 8);
        }
        __syncthreads();

        s8v ah[4], al[4], bh[4], bl[4];
        #pragma unroll
        for (int i = 0; i < 4; ++i) {
            ah[i] = *(const s8v*)&AsH[kg][wm * 64 + i * 16 + li][0];
            al[i] = *(const s8v*)&AsL[kg][wm * 64 + i * 16 + li][0];
            bh[i] = *(const s8v*)&BsH[kg][wn * 64 + i * 16 + li][0];
            bl[i] = *(const s8v*)&BsL[kg][wn * 64 + i * 16 + li][0];
        }
        #pragma unroll
        for (int i = 0; i < 4; ++i)
            #pragma unroll
            for (int j = 0; j < 4; ++j) {
                acc[i][j] = __builtin_amdgcn_mfma_f32_16x16x32_bf16(ah[i], bh[j], acc[i][j], 0, 0, 0);
                acc[i][j] = __builtin_amdgcn_mfma_f32_16x16x32_bf16(ah[i], bl[j], acc[i][j], 0, 0, 0);
                acc[i][j] = __builtin_amdgcn_mfma_f32_16x16x32_bf16(al[i], bh[j], acc[i][j], 0, 0, 0);
            }
        __syncthreads();
    }

    // epilogue: bias + act + fp32 store. C frag: col=lane&15, row=(lane>>4)*4+reg
    #pragma unroll
    for (int j = 0; j < 4; ++j) {
        int col = bn + wn * 64 + j * 16 + li;
        float b = bias[col];
        #pragma unroll
        for (int i = 0; i < 4; ++i) {
            int row0 = bm + wm * 64 + i * 16 + kg * 4;
            #pragma unroll
            for (int r = 0; r < 4; ++r) {
                int row = row0 + r;
                if (row < M) {
                    float vv = acc[i][j][r] + b;
                    vv = (act == 2) ? tanhf(vv) : fmaxf(vv, 0.f);
                    Cout[(size_t)row * N + col] = vv;
                }
            }
        }
    }
}

// ---------------- launch ----------------

extern "C" void kernel_launch(void* const* d_in, const int* in_sizes, int n_in,
                              void* d_out, int out_size, void* d_ws, size_t ws_size,
                              hipStream_t stream) {
    const float* feat = (const float*)d_in[0];
    const int* einfo = (const int*)d_in[1];
    const float* b1 = (const float*)d_in[3];
    const float* b2 = (const float*)d_in[5];
    const float* b3 = (const float*)d_in[7];
    const float* bl1 = (const float*)d_in[9];
    const float* blH = (const float*)d_in[12];
    const float* bl2 = (const float*)d_in[15];
    const float* bp1 = (const float*)d_in[18];
    const float* bp2 = (const float*)d_in[20];
    const float* bp3 = (const float*)d_in[22];

    const int IN_DIM = 512, HID = 256, OUT = 128;
    const int N = in_sizes[0] / IN_DIM;   // 50000
    const int E = in_sizes[1] / 2;        // 400000
    const int* src = einfo;
    const int* dst = einfo + E;

    float* bufA = (float*)d_ws;
    float* bufB = bufA + (size_t)N * HID;
    float* bufC = bufB + (size_t)N * HID;
    int* ioff = (int*)(bufC + (size_t)N * HID);
    int* icnt = ioff + (N + 1);
    int* icur = icnt + N;
    int* csr = icur + N;
    ushort* wsp = (ushort*)(csr + E);

    // weight table: {d_in idx, K, N}
    const int widx[12] = {2, 4, 6, 8, 10, 11, 13, 14, 16, 17, 19, 21};
    const int wK[12] = {512, 256, 256, 256, 256, 256, 256, 256, 256, 256, 256, 256};
    const int wN[12] = {256, 256, 256, 256, 256, 256, 256, 256, 256, 256, 256, 128};

    PrepArgs pa;
    ushort* Hp[12]; ushort* Lp[12];
    int acc_end = 0;
    ushort* cur = wsp;
    for (int i = 0; i < 12; ++i) {
        int elems = wK[i] * wN[i];
        pa.W[i] = (const float*)d_in[widx[i]];
        Hp[i] = cur; cur += elems;
        Lp[i] = cur; cur += elems;
        pa.H[i] = Hp[i];
        pa.L[i] = Lp[i];
        acc_end += elems;
        pa.end[i] = acc_end;
        pa.Kv[i] = wK[i];
        pa.nshift[i] = (wN[i] == 256) ? 8 : 7;
    }

    // CSR build
    hipMemsetAsync(icnt, 0, (size_t)N * sizeof(int), stream);
    hipMemsetAsync(icur, 0, (size_t)N * sizeof(int), stream);
    hist_kernel<<<(E + 255) / 256, 256, 0, stream>>>(dst, icnt, E);
    scan_kernel<<<1, 1024, 0, stream>>>(icnt, ioff, N);
    scatter_kernel<<<(E + 255) / 256, 256, 0, stream>>>(src, dst, icur, ioff, csr, E);
    prep_weights<<<(acc_end + 255) / 256, 256, 0, stream>>>(pa, acc_end);

    auto gemm = [&](const float* A1, int K1, const float* A2, int K2,
                    int w1, int w2, const float* bias, float* C, int Nc, int act) {
        dim3 g(Nc / 128, (N + 127) / 128);
        gemm_split_kernel<<<g, 256, 0, stream>>>(
            A1, K1, A2, K2, Hp[w1], Lp[w1],
            (w2 >= 0) ? Hp[w2] : nullptr, (w2 >= 0) ? Lp[w2] : nullptr,
            bias, C, N, Nc, act);
    };

    // MLP stem
    gemm(feat, IN_DIM, nullptr, 0, 0, -1, b1, bufA, HID, 1);
    gemm(bufA, HID, nullptr, 0, 1, -1, b2, bufB, HID, 1);
    gemm(bufB, HID, nullptr, 0, 2, -1, b3, bufA, HID, 1);

    // SAGE layer 1: x = bufA
    sage_aggr4<<<(N + 3) / 4, 256, 0, stream>>>(bufA, csr, ioff, bufC, N);
    gemm(bufC, HID, bufA, HID, 3, 4, bl1, bufB, HID, 1);

    // SAGE layer 2: x = bufB
    sage_aggr4<<<(N + 3) / 4, 256, 0, stream>>>(bufB, csr, ioff, bufC, N);
    gemm(bufC, HID, bufB, HID, 5, 6, blH, bufA, HID, 1);

    // SAGE layer 3: x = bufA
    sage_aggr4<<<(N + 3) / 4, 256, 0, stream>>>(bufA, csr, ioff, bufC, N);
    gemm(bufC, HID, bufA, HID, 7, 8, bl2, bufB, HID, 1);

    // MLP head
    gemm(bufB, HID, nullptr, 0, 9, -1, bp1, bufA, HID, 1);
    gemm(bufA, HID, nullptr, 0, 10, -1, bp2, bufC, HID, 1);
    gemm(bufC, HID, nullptr, 0, 11, -1, bp3, (float*)d_out, OUT, 2);
}